// Round 7
// baseline (253.759 us; speedup 1.0000x reference)
//
#include <hip/hip_runtime.h>

typedef __attribute__((ext_vector_type(8))) short bf16x8;
typedef __attribute__((ext_vector_type(4))) float f32x4;
typedef unsigned short u16;
typedef unsigned int u32;
typedef __attribute__((address_space(1))) const u32 gu32;
typedef __attribute__((address_space(3))) u32 lu32;

__device__ __forceinline__ float bf2f(u16 u) {
  union { u32 i; float f; } c; c.i = ((u32)u) << 16; return c.f;
}
__device__ __forceinline__ u16 f2bf(float f) {
  union { float f; u32 i; } c; c.f = f;
  u32 u = c.i;
  u32 r = (u + 0x7FFFu + ((u >> 16) & 1u)) >> 16;  // RNE
  return (u16)r;
}

// async 16B global->LDS (linear dest: wave-uniform base + lane*16)
__device__ __forceinline__ void gld16(const void* g, void* l) {
  __builtin_amdgcn_global_load_lds((gu32*)g, (lu32*)l, 16, 0, 0);
}

// ---------------- CSR / normalization build ----------------

__global__ void k_count(const int* __restrict__ ei, int* deg, int E) {
  int e = blockIdx.x * 256 + threadIdx.x;
  if (e < E) atomicAdd(&deg[ei[E + e]], 1);  // dst = edge_index[1][e]
}

__global__ void k_blocksum(const int* __restrict__ deg, int* bsum, int n) {
  __shared__ int s[256];
  int t = threadIdx.x;
  int i = blockIdx.x * 256 + t;
  s[t] = (i < n) ? deg[i] : 0;
  __syncthreads();
  for (int o = 128; o > 0; o >>= 1) {
    if (t < o) s[t] += s[t + o];
    __syncthreads();
  }
  if (t == 0) bsum[blockIdx.x] = s[0];
}

__global__ void k_scanb(const int* __restrict__ bsum, int* bofs, int nb) {
  __shared__ int s[256];
  int t = threadIdx.x;
  int v = (t < nb) ? bsum[t] : 0;
  s[t] = v;
  __syncthreads();
  for (int o = 1; o < 256; o <<= 1) {
    int x = (t >= o) ? s[t - o] : 0;
    __syncthreads();
    s[t] += x;
    __syncthreads();
  }
  bofs[t] = s[t] - v;  // exclusive
}

__global__ void k_rowptr(const int* __restrict__ deg, const int* __restrict__ bofs,
                         int* rowptr, int* cursor, float* dinv, int n) {
  __shared__ int s[256];
  int t = threadIdx.x;
  int i = blockIdx.x * 256 + t;
  int v = (i < n) ? deg[i] : 0;
  s[t] = v;
  __syncthreads();
  for (int o = 1; o < 256; o <<= 1) {
    int x = (t >= o) ? s[t - o] : 0;
    __syncthreads();
    s[t] += x;
    __syncthreads();
  }
  int excl = s[t] - v + bofs[blockIdx.x];
  if (i < n) {
    rowptr[i] = excl;
    cursor[i] = excl;
    dinv[i] = rsqrtf((float)(v + 1));  // +1 self-loop
    if (i == n - 1) rowptr[n] = excl + v;
  }
}

// pack (src, dinv[src]) per edge
__global__ void k_fill(const int* __restrict__ ei, int* cursor,
                       const float* __restrict__ dinv, int2* colw, int E) {
  int e = blockIdx.x * 256 + threadIdx.x;
  if (e >= E) return;
  int s = ei[e];
  int d = ei[E + e];
  int pos = atomicAdd(&cursor[d], 1);
  colw[pos] = make_int2(s, __float_as_int(dinv[s]));
}

// transpose + bf16 both weights in one launch: W[K][N] f32 -> Wt[N][K] bf16
__global__ void k_twt2(const float* __restrict__ W1, u16* __restrict__ W1t,
                       const float* __restrict__ W2, u16* __restrict__ W2t) {
  int i = blockIdx.x * 256 + threadIdx.x;
  if (i < 512 * 256) {
    int k = i >> 8, n = i & 255;
    W1t[n * 512 + k] = f2bf(W1[i]);
  } else {
    int j = i - 512 * 256;
    if (j < 256 * 128) {
      int k = j >> 7, n = j & 127;
      W2t[n * 256 + k] = f2bf(W2[j]);
    }
  }
}

// ---------------- GEMM v3: barrier-free streaming ----------------
// C[M,ldc](bf16) = A[M,K] @ Bt[*,K]^T.
// Block: 1024 thr (16 waves), 256 rows x COLS cols. The ENTIRE B panel
// (COLS x K bf16, k-slab layout with the proven u^(c&3) swizzle) is staged
// into LDS once via global_load_lds + ONE barrier. K-loop has NO barriers:
// A streams global->reg (each lane's MFMA A-frag = contiguous 32B/16B chunk,
// coalesced per 128B row segment), PF=2 prefetch, fully unrolled (static
// slots), fp32->bf16 via v_cvt_pk in regs. Waves run independently; latency
// hidden by 4 waves/SIMD TLP instead of barrier-coupled double-buffering.

template <bool AF32, int K, int COLS>
__launch_bounds__(1024)
__global__ void gemm3(const void* __restrict__ Ap, const u16* __restrict__ Bt,
                      u16* __restrict__ C, int M, int ldc) {
  constexpr int NT = K / 32;
  constexpr int SLABU = COLS * 4;             // 16B units per k-slab
  constexpr int NB = (COLS * K / 8) / 1024;   // staging units per thread
  constexpr int NJ = COLS / 16;               // col frags per wave
  __shared__ __align__(16) u16 Bs[NT][COLS * 32];

  const int tid = threadIdx.x;
  const int lane = tid & 63;
  const int w = tid >> 6;
  const long brow = (long)blockIdx.y * 256;
  const long bcol = (long)blockIdx.x * COLS;

  // ---- stage full B panel once (pre-swizzled source, linear LDS dest) ----
#pragma unroll
  for (int j = 0; j < NB; ++j) {
    int g = j * 1024 + tid;
    int kt = g / SLABU;
    int s = g - kt * SLABU;
    int c = s >> 2;
    int u = (s & 3) ^ (c & 3);
    gld16(Bt + (bcol + c) * (long)K + kt * 32 + u * 8,
          (char*)&Bs[0][0] + (size_t)g * 16);
  }
  __syncthreads();  // compiler drains vmcnt(0) here — the ONLY barrier

  // ---- A stream setup ----
  long arow = brow + w * 16 + (lane & 15);
  if (arow > (long)M - 1) arow = M - 1;  // clamp: rows>=M never stored
  const char* ap = (const char*)Ap + (arow * (long)K + (lane >> 4) * 8) * (AF32 ? 4 : 2);
  constexpr int AST = 32 * (AF32 ? 4 : 2);  // bytes per K-step per lane-row

  f32x4 acc[NJ];
#pragma unroll
  for (int j = 0; j < NJ; ++j) acc[j] = (f32x4){0.f, 0.f, 0.f, 0.f};

  float4 fa[2][2];
  uint4 fb[2];
  auto loadA = [&](int kt, int sl) {
    if constexpr (AF32) {
      fa[sl][0] = *(const float4*)(ap + (size_t)kt * AST);
      fa[sl][1] = *(const float4*)(ap + (size_t)kt * AST + 16);
    } else {
      fb[sl] = *(const uint4*)(ap + (size_t)kt * AST);
    }
  };
  loadA(0, 0);
  loadA(1, 1);

#pragma unroll
  for (int kt = 0; kt < NT; ++kt) {
    const int sl = kt & 1;  // compile-time after unroll (rule #20)
    bf16x8 af;
    if constexpr (AF32) {
      union { u32 wd[4]; bf16x8 v; } cv;
      asm("v_cvt_pk_bf16_f32 %0, %1, %2" : "=v"(cv.wd[0]) : "v"(fa[sl][0].x), "v"(fa[sl][0].y));
      asm("v_cvt_pk_bf16_f32 %0, %1, %2" : "=v"(cv.wd[1]) : "v"(fa[sl][0].z), "v"(fa[sl][0].w));
      asm("v_cvt_pk_bf16_f32 %0, %1, %2" : "=v"(cv.wd[2]) : "v"(fa[sl][1].x), "v"(fa[sl][1].y));
      asm("v_cvt_pk_bf16_f32 %0, %1, %2" : "=v"(cv.wd[3]) : "v"(fa[sl][1].z), "v"(fa[sl][1].w));
      af = cv.v;
    } else {
      union { uint4 q; bf16x8 v; } cv2;
      cv2.q = fb[sl];
      af = cv2.v;
    }
    if (kt + 2 < NT) loadA(kt + 2, sl);  // refill slot (SSA rename, no hazard)
#pragma unroll
    for (int j = 0; j < NJ; ++j) {
      const int row = j * 16 + (lane & 15);
      const int u = (lane >> 4) ^ (row & 3);
      bf16x8 bq = *(const bf16x8*)&Bs[kt][row * 32 + u * 8];
      acc[j] = __builtin_amdgcn_mfma_f32_16x16x32_bf16(af, bq, acc[j], 0, 0, 0);
    }
  }

  // ---- epilogue ----
#pragma unroll
  for (int j = 0; j < NJ; ++j) {
    const long cc = bcol + j * 16 + (lane & 15);
    const long r0 = brow + w * 16 + ((lane >> 4) * 4);
#pragma unroll
    for (int q = 0; q < 4; ++q) {
      long r = r0 + q;
      if (r < M) C[r * (long)ldc + cc] = f2bf(acc[j][q]);
    }
  }
}

// ---------------- Aggregation (one wave per node, full-row gather) ----------------

__device__ __forceinline__ float sigmoidf_(float x) { return 1.f / (1.f + __expf(-x)); }

__launch_bounds__(256)
__global__ void agg1(const u16* __restrict__ h0, const int* __restrict__ rowptr,
                     const int2* __restrict__ colw, const float* __restrict__ dinv,
                     const float* __restrict__ b1, u16* __restrict__ h, int n) {
  const int wid = threadIdx.x >> 6, lane = threadIdx.x & 63;
  const int node = blockIdx.x * 4 + wid;
  if (node >= n) return;
  const float di = dinv[node];
  ushort4 sv = ((const ushort4*)(h0 + (size_t)node * 256))[lane];
  float a0 = di * bf2f(sv.x), a1 = di * bf2f(sv.y), a2 = di * bf2f(sv.z), a3 = di * bf2f(sv.w);
  int e = rowptr[node];
  const int r1 = rowptr[node + 1];
  for (; e + 8 <= r1; e += 8) {
    int2 c[8];
#pragma unroll
    for (int q = 0; q < 8; ++q) c[q] = colw[e + q];
    ushort4 v[8];
#pragma unroll
    for (int q = 0; q < 8; ++q)
      v[q] = ((const ushort4*)(h0 + (size_t)c[q].x * 256))[lane];
#pragma unroll
    for (int q = 0; q < 8; ++q) {
      float wv = __int_as_float(c[q].y);
      a0 += wv * bf2f(v[q].x); a1 += wv * bf2f(v[q].y);
      a2 += wv * bf2f(v[q].z); a3 += wv * bf2f(v[q].w);
    }
  }
  for (; e < r1; ++e) {
    int2 c = colw[e];
    float wv = __int_as_float(c.y);
    ushort4 v = ((const ushort4*)(h0 + (size_t)c.x * 256))[lane];
    a0 += wv * bf2f(v.x); a1 += wv * bf2f(v.y); a2 += wv * bf2f(v.z); a3 += wv * bf2f(v.w);
  }
  float4 bb = ((const float4*)b1)[lane];
  a0 = a0 * di + bb.x; a1 = a1 * di + bb.y; a2 = a2 * di + bb.z; a3 = a3 * di + bb.w;
  a0 = fmaxf(a0, 0.f); a1 = fmaxf(a1, 0.f); a2 = fmaxf(a2, 0.f); a3 = fmaxf(a3, 0.f);
  ushort4 o; o.x = f2bf(a0); o.y = f2bf(a1); o.z = f2bf(a2); o.w = f2bf(a3);
  ((ushort4*)(h + (size_t)node * 256))[lane] = o;
}

__launch_bounds__(256)
__global__ void agg2(const u16* __restrict__ h2, const int* __restrict__ rowptr,
                     const int2* __restrict__ colw, const float* __restrict__ dinv,
                     const float* __restrict__ b2, float* __restrict__ out, int n) {
  const int wid = threadIdx.x >> 6, lane = threadIdx.x & 63;
  const int node = blockIdx.x * 4 + wid;
  if (node >= n) return;
  const float di = dinv[node];
  ushort2 sv = ((const ushort2*)(h2 + (size_t)node * 128))[lane];
  float a0 = di * bf2f(sv.x), a1 = di * bf2f(sv.y);
  int e = rowptr[node];
  const int r1 = rowptr[node + 1];
  for (; e + 8 <= r1; e += 8) {
    int2 c[8];
#pragma unroll
    for (int q = 0; q < 8; ++q) c[q] = colw[e + q];
    ushort2 v[8];
#pragma unroll
    for (int q = 0; q < 8; ++q)
      v[q] = ((const ushort2*)(h2 + (size_t)c[q].x * 128))[lane];
#pragma unroll
    for (int q = 0; q < 8; ++q) {
      float wv = __int_as_float(c[q].y);
      a0 += wv * bf2f(v[q].x); a1 += wv * bf2f(v[q].y);
    }
  }
  for (; e < r1; ++e) {
    int2 c = colw[e];
    float wv = __int_as_float(c.y);
    ushort2 v = ((const ushort2*)(h2 + (size_t)c.x * 128))[lane];
    a0 += wv * bf2f(v.x); a1 += wv * bf2f(v.y);
  }
  float2 bb = ((const float2*)b2)[lane];
  float2 o;
  o.x = sigmoidf_(a0 * di + bb.x);
  o.y = sigmoidf_(a1 * di + bb.y);
  ((float2*)(out + (size_t)node * 128))[lane] = o;
}

// ---------------- launch ----------------

extern "C" void kernel_launch(void* const* d_in, const int* in_sizes, int n_in,
                              void* d_out, int out_size, void* d_ws, size_t ws_size,
                              hipStream_t stream) {
  const float* x  = (const float*)d_in[0];
  const float* W1 = (const float*)d_in[1];
  const float* b1 = (const float*)d_in[2];
  const float* W2 = (const float*)d_in[3];
  const float* b2 = (const float*)d_in[4];
  const int*   ei = (const int*)d_in[5];

  const int N = in_sizes[0] / 512;
  const int E = in_sizes[5] / 2;
  const int Mpad = (N + 127) & ~127;
  float* outp = (float*)d_out;

  char* w = (char*)d_ws;
  size_t off = 0;
  auto take = [&](size_t bytes) -> void* {
    void* p = w + off;
    off = (off + bytes + 255) & ~(size_t)255;
    return p;
  };
  u16*   h0     = (u16*)take((size_t)Mpad * 256 * 2);
  u16*   hb     = (u16*)take((size_t)Mpad * 256 * 2);
  u16*   h2     = (u16*)take((size_t)Mpad * 128 * 2);
  u16*   W1t    = (u16*)take(256 * 512 * 2);
  u16*   W2t    = (u16*)take(128 * 256 * 2);
  int*   deg    = (int*)take((size_t)N * 4);
  float* dinv   = (float*)take((size_t)N * 4);
  int*   rowptr = (int*)take((size_t)(N + 1) * 4);
  int*   cursor = (int*)take((size_t)N * 4);
  int2*  colw   = (int2*)take((size_t)E * 8);
  int*   bsum   = (int*)take(256 * 4);
  int*   bofs   = (int*)take(256 * 4);
  (void)ws_size; (void)n_in; (void)out_size;

  const int nb = (N + 255) / 256;  // <=256 required by k_scanb
  const int eb = (E + 255) / 256;

  hipMemsetAsync(deg, 0, (size_t)N * 4, stream);
  k_count<<<eb, 256, 0, stream>>>(ei, deg, E);
  k_blocksum<<<nb, 256, 0, stream>>>(deg, bsum, N);
  k_scanb<<<1, 256, 0, stream>>>(bsum, bofs, nb);
  k_rowptr<<<nb, 256, 0, stream>>>(deg, bofs, rowptr, cursor, dinv, N);
  k_fill<<<eb, 256, 0, stream>>>(ei, cursor, dinv, colw, E);
  k_twt2<<<(512 * 256 + 256 * 128 + 255) / 256, 256, 0, stream>>>(W1, W1t, W2, W2t);

  const int rb = (N + 255) / 256;  // 256-row panels
  dim3 g1(2, rb);                  // x = col-tile (fast) -> A panel L2/L3 reuse
  gemm3<true, 512, 128><<<g1, 1024, 0, stream>>>((const void*)x, W1t, h0, N, 256);
  agg1<<<(N + 3) / 4, 256, 0, stream>>>(h0, rowptr, colw, dinv, b1, hb, N);
  dim3 g2(1, rb);
  gemm3<false, 256, 128><<<g2, 1024, 0, stream>>>((const void*)hb, W2t, h2, N, 128);
  agg2<<<(N + 3) / 4, 256, 0, stream>>>(h2, rowptr, colw, dinv, b2, outp, N);
}